// Round 11
// baseline (106.209 us; speedup 1.0000x reference)
//
#include <hip/hip_runtime.h>

// Problem constants (from reference setup_inputs)
#define BB 2
#define CC 16
#define TT 8
#define HH 64
#define WW 64
#define CO 16
#define KK 27          // 3*3*3 taps
#define THW (TT*HH*WW) // 32768
#define HW  (HH*WW)    // 4096

typedef _Float16 h2   __attribute__((ext_vector_type(2)));   // 4 B
typedef _Float16 h8   __attribute__((ext_vector_type(8)));   // 16 B
typedef _Float16 h16  __attribute__((ext_vector_type(16)));  // 32 B

#define NROW 13        // tile rows [h0-5, h0+7]  (covers |off| <= 4)
#define ROWB 2048      // bytes per staged row: 64 cols * 16 ch * 2 B
#define TILEB (3 * NROW * ROWB)   // 79872 B

#if __has_builtin(__builtin_amdgcn_fdot2)
#define FDOT2(a, b, c) __builtin_amdgcn_fdot2((a), (b), (c), false)
#else
static __device__ __forceinline__ float FDOT2(h2 a, h2 b, float c) {
    return c + (float)a[0] * (float)b[0] + (float)a[1] * (float)b[1];
}
#endif

// ---------------------------------------------------------------------------
// Prep: blocks [0,256): x [B,C,T,H,W] -> xT [B,T,H,W,C] fp16 (32 B/pos)
//       block 256      : weight [Co,C,27] -> wP[k][c2][co] packed h2 dwords
//                        (.x = w[co][2*c2][k], .y = w[co][2*c2+1][k])
// ---------------------------------------------------------------------------
__global__ __launch_bounds__(256) void prep(const float* __restrict__ x,
                                            const float* __restrict__ w,
                                            _Float16* __restrict__ xT,
                                            unsigned* __restrict__ wP) {
    int bid = blockIdx.x;
    if (bid < 256) {
        int pos = bid * 256 + threadIdx.x;          // B*T*H*W = 65536
        int b = pos / THW;
        int s = pos - b * THW;
        h16 hv;
#pragma unroll
        for (int c = 0; c < CC; ++c)
            hv[c] = (_Float16)x[(size_t)(b * CC + c) * THW + s];
        *(h16*)(xT + (size_t)pos * CC) = hv;
    } else {
        // 3456 dwords = 27 * 8 * 16
#pragma unroll
        for (int it = 0; it < 14; ++it) {
            int id = it * 256 + threadIdx.x;
            if (id < KK * 8 * CO) {
                int k  = id >> 7;
                int c2 = (id >> 4) & 7;
                int co = id & 15;
                _Float16 lo = (_Float16)w[(size_t)(co * CC + 2 * c2)     * KK + k];
                _Float16 hi = (_Float16)w[(size_t)(co * CC + 2 * c2 + 1) * KK + k];
                unsigned u = (unsigned)__builtin_bit_cast(unsigned short, lo)
                           | ((unsigned)__builtin_bit_cast(unsigned short, hi) << 16);
                wP[id] = u;
            }
        }
    }
}

// XOR swizzle (proven R7/R10): spread bank-group bits; bijective; SAME
// function on write and read side.
__device__ __forceinline__ int swz(int rr, int c, int base) {
    int sw = ((((c >> 2) ^ rr) & 3) << 4) | (((c >> 4) & 1) << 6);
    return base ^ sw;
}

// ---------------------------------------------------------------------------
// Main: 512 threads = 8 waves = 2 output rows x 4 tap-groups; 64 pos/wave.
// R10 structure, with the weight path moved from SMEM (s_load, lgkmcnt,
// out-of-order -> forced lgkmcnt(0) drains that serialize with gather
// ds_reads) to VMEM (global_load_dwordx4 on vmcnt, L1-hot 13.8 KB table,
// address laundered through an opaque-zero VGPR so the compiler cannot
// scalarize). Contraction via v_dot2_f32_f16 on packed fp16 weights.
// ---------------------------------------------------------------------------
__global__ __launch_bounds__(512, 4) void deform_lds4(
    const _Float16* __restrict__ xT, const float* __restrict__ temp,
    const unsigned* __restrict__ wP, const float* __restrict__ bias,
    float* __restrict__ out)
{
    __shared__ __align__(16) char lds[TILEB];       // 79872 B

    int tid = threadIdx.x;
    int lane = tid & 63;
    int wid  = __builtin_amdgcn_readfirstlane(tid >> 6);   // 0..7
    int row  = wid >> 2;                            // output row 0/1
    int g    = wid & 3;                             // tap group 0..3
    int blk = blockIdx.x;                           // 512 = B*T*(H/2)
    int b   = blk >> 8;
    int rem = blk & 255;
    int t   = rem >> 5;
    int h0  = (rem & 31) * 2;
    int rlo = max(0, h0 - 5);
    int rhi = min(HH - 1, h0 + 7);

    int vz = 0;
    asm volatile("" : "+v"(vz));                    // opaque zero in a VGPR

    int h = h0 + row;
    int w = lane;
    const float* tb = temp + (size_t)b * (2 * KK) * THW
                    + (size_t)t * HW + h * WW + w;

    // ---- issue this wave's tap offsets FIRST (latency hides under staging)
    float offh[7], offw[7];
#pragma unroll
    for (int i = 0; i < 7; ++i) {
        int k = g + 4 * i;
        if (k < KK) {
            offh[i] = tb[(size_t)(2 * k)     * THW];
            offw[i] = tb[(size_t)(2 * k + 1) * THW];
        }
    }

    // ---- cooperative staging: 4992 coalesced 16B chunks over 512 threads
    {
        const int nchunk = 3 * NROW * 128;          // 4992
#pragma unroll
        for (int it = 0; it < 10; ++it) {
            int chunk = tid + it * 512;
            if (chunk >= nchunk) break;
            int kt  = chunk / (NROW * 128);
            int r2  = chunk - kt * (NROW * 128);
            int rr  = r2 >> 7;
            int j   = r2 & 127;                     // 16B chunk in row
            int pt  = t - 1 + kt;
            int r   = rlo + rr;
            if (pt >= 0 && pt < TT && r <= rhi) {
                const h8* src = (const h8*)(xT +
                    (size_t)((b * TT + pt) * HW + r * WW) * CC) + j;
                int dst = kt * (NROW * ROWB) + rr * ROWB + j * 16;
                *(h8*)(lds + swz(rr, j >> 1, dst)) = *src;
            }
        }
    }
    __syncthreads();

    float acc[CO];
#pragma unroll
    for (int j = 0; j < CO; ++j) acc[j] = 0.f;

#pragma unroll
    for (int i = 0; i < 7; ++i) {
        int k = g + 4 * i;
        if (k >= KK) continue;                      // wave-uniform
        int kt = k / 9, kh = (k / 3) % 3, kw = k % 3;
        int pt = t - 1 + kt;                        // offset_t == 0 exactly
        if (pt < 0 || pt >= TT) continue;           // block-uniform

        float ph = (float)(h - 1 + kh) + offh[i];
        float pw = (float)(w - 1 + kw) + offw[i];
        float r0f = floorf(ph), w0f = floorf(pw);
        float fh = ph - r0f, fw = pw - w0f;
        int r0 = (int)r0f, w0i = (int)w0f;
        int r1 = r0 + 1, w1i = w0i + 1;
        bool vh0 = (unsigned)r0  < (unsigned)HH;
        bool vh1 = (unsigned)r1  < (unsigned)HH;
        bool vw0 = (unsigned)w0i < (unsigned)WW;
        bool vw1 = (unsigned)w1i < (unsigned)WW;
        float fh1 = 1.f - fh, fw1 = 1.f - fw;
        float c00 = fh1 * fw1 * ((vh0 && vw0) ? 1.f : 0.f);
        float c01 = fh1 * fw  * ((vh0 && vw1) ? 1.f : 0.f);
        float c10 = fh  * fw1 * ((vh1 && vw0) ? 1.f : 0.f);
        float c11 = fh  * fw  * ((vh1 && vw1) ? 1.f : 0.f);
        int cc0 = min(max(w0i, 0), WW - 1);
        int cc1 = min(max(w1i, 0), WW - 1);
        int rr0 = min(max(r0, rlo), rhi) - rlo;
        int rr1 = min(max(r1, rlo), rhi) - rlo;
        int pb = kt * (NROW * ROWB);

        h8 q00a = *(const h8*)(lds + swz(rr0, cc0, pb + rr0 * ROWB + cc0 * 32));
        h8 q00b = *(const h8*)(lds + swz(rr0, cc0, pb + rr0 * ROWB + cc0 * 32 + 16));
        h8 q01a = *(const h8*)(lds + swz(rr0, cc1, pb + rr0 * ROWB + cc1 * 32));
        h8 q01b = *(const h8*)(lds + swz(rr0, cc1, pb + rr0 * ROWB + cc1 * 32 + 16));
        h8 q10a = *(const h8*)(lds + swz(rr1, cc0, pb + rr1 * ROWB + cc0 * 32));
        h8 q10b = *(const h8*)(lds + swz(rr1, cc0, pb + rr1 * ROWB + cc0 * 32 + 16));
        h8 q11a = *(const h8*)(lds + swz(rr1, cc1, pb + rr1 * ROWB + cc1 * 32));
        h8 q11b = *(const h8*)(lds + swz(rr1, cc1, pb + rr1 * ROWB + cc1 * 32 + 16));

        // rare |off|>4 fallback: valid sample row outside staged tile
        bool ob0 = vh0 && (r0 < rlo || r0 > rhi);
        bool ob1 = vh1 && (r1 < rlo || r1 > rhi);
        if (__builtin_expect(__any(ob0 || ob1), 0)) {
            const h8* xg = (const h8*)(xT + (size_t)((b * TT + pt) * HW) * CC);
            if (ob0) {
                q00a = xg[(r0 * WW + cc0) * 2];
                q00b = xg[(r0 * WW + cc0) * 2 + 1];
                q01a = xg[(r0 * WW + cc1) * 2];
                q01b = xg[(r0 * WW + cc1) * 2 + 1];
            }
            if (ob1) {
                q10a = xg[(r1 * WW + cc0) * 2];
                q10b = xg[(r1 * WW + cc0) * 2 + 1];
                q11a = xg[(r1 * WW + cc1) * 2];
                q11b = xg[(r1 * WW + cc1) * 2 + 1];
            }
        }

        // packed fp16 bilinear interp
        _Float16 h00 = (_Float16)c00, h01 = (_Float16)c01;
        _Float16 h10 = (_Float16)c10, h11 = (_Float16)c11;
        h8 va = q00a * h00 + q01a * h01 + q10a * h10 + q11a * h11; // c0..7
        h8 vb = q00b * h00 + q01b * h01 + q10b * h10 + q11b * h11; // c8..15

        // contraction via v_dot2_f32_f16; weights from VMEM (vmcnt), L1-hot
        const unsigned* wb = wP + k * 128 + vz;     // vz==0, opaque -> VMEM
#pragma unroll
        for (int c2 = 0; c2 < 8; ++c2) {
            _Float16 a0 = (c2 < 4) ? va[2 * c2]     : vb[2 * c2 - 8];
            _Float16 a1 = (c2 < 4) ? va[2 * c2 + 1] : vb[2 * c2 - 7];
            h2 aa = {a0, a1};
            uint4 w0 = *(const uint4*)(wb + c2 * 16);
            uint4 w1 = *(const uint4*)(wb + c2 * 16 + 4);
            uint4 w2 = *(const uint4*)(wb + c2 * 16 + 8);
            uint4 w3 = *(const uint4*)(wb + c2 * 16 + 12);
            acc[ 0] = FDOT2(aa, __builtin_bit_cast(h2, w0.x), acc[ 0]);
            acc[ 1] = FDOT2(aa, __builtin_bit_cast(h2, w0.y), acc[ 1]);
            acc[ 2] = FDOT2(aa, __builtin_bit_cast(h2, w0.z), acc[ 2]);
            acc[ 3] = FDOT2(aa, __builtin_bit_cast(h2, w0.w), acc[ 3]);
            acc[ 4] = FDOT2(aa, __builtin_bit_cast(h2, w1.x), acc[ 4]);
            acc[ 5] = FDOT2(aa, __builtin_bit_cast(h2, w1.y), acc[ 5]);
            acc[ 6] = FDOT2(aa, __builtin_bit_cast(h2, w1.z), acc[ 6]);
            acc[ 7] = FDOT2(aa, __builtin_bit_cast(h2, w1.w), acc[ 7]);
            acc[ 8] = FDOT2(aa, __builtin_bit_cast(h2, w2.x), acc[ 8]);
            acc[ 9] = FDOT2(aa, __builtin_bit_cast(h2, w2.y), acc[ 9]);
            acc[10] = FDOT2(aa, __builtin_bit_cast(h2, w2.z), acc[10]);
            acc[11] = FDOT2(aa, __builtin_bit_cast(h2, w2.w), acc[11]);
            acc[12] = FDOT2(aa, __builtin_bit_cast(h2, w3.x), acc[12]);
            acc[13] = FDOT2(aa, __builtin_bit_cast(h2, w3.y), acc[13]);
            acc[14] = FDOT2(aa, __builtin_bit_cast(h2, w3.z), acc[14]);
            acc[15] = FDOT2(aa, __builtin_bit_cast(h2, w3.w), acc[15]);
        }
    }

    // ---- cross-group reduction: reuse staging LDS ----
    __syncthreads();                                // all tap reads done
    float* red = (float*)lds;                       // [row][g][co][pos]
#pragma unroll
    for (int jj = 0; jj < CO; ++jj)
        red[((row * 4 + g) * CO + jj) * 64 + w] = acc[jj];
    __syncthreads();

#pragma unroll
    for (int it = 0; it < 4; ++it) {
        int idx = tid + it * 512;                   // 2048 (row,co,pos) outs
        int row2 = idx >> 10;
        int co   = (idx >> 6) & 15;
        int p    = idx & 63;
        float sum = bias[co];
#pragma unroll
        for (int gg = 0; gg < 4; ++gg)
            sum += red[((row2 * 4 + gg) * CO + co) * 64 + p];
        out[(size_t)b * CO * THW + (size_t)co * THW
            + t * HW + (h0 + row2) * WW + p] = sum;
    }
}

// ---------------------------------------------------------------------------
// Safety fallback if workspace is too small: direct fp32 global-gather.
// ---------------------------------------------------------------------------
__global__ __launch_bounds__(256) void deform_global(
    const float* __restrict__ x, const float* __restrict__ temp,
    const float* __restrict__ weight, const float* __restrict__ bias,
    float* __restrict__ out)
{
    int pos = blockIdx.x * 256 + threadIdx.x;
    int b = pos / THW, s = pos - b * THW;
    int t = s / HW, hw = s - t * HW, h = hw >> 6, w = hw & 63;
    float acc[CO];
#pragma unroll
    for (int co = 0; co < CO; ++co) acc[co] = bias[co];
#pragma unroll 1
    for (int k = 0; k < KK; ++k) {
        int kt = k / 9, kh = (k / 3) % 3, kw = k % 3;
        int pt = t - 1 + kt;
        if (pt < 0 || pt >= TT) continue;
        const float* tb = temp + (size_t)b * (2 * KK) * THW + s;
        float ph = (float)(h - 1 + kh) + tb[(size_t)(2 * k) * THW];
        float pw = (float)(w - 1 + kw) + tb[(size_t)(2 * k + 1) * THW];
        float h0f = floorf(ph), w0f = floorf(pw);
        float fh = ph - h0f, fw = pw - w0f;
        int h0 = (int)h0f, w0 = (int)w0f;
        float val[CC];
#pragma unroll
        for (int c = 0; c < CC; ++c) val[c] = 0.f;
#pragma unroll
        for (int dh = 0; dh < 2; ++dh) {
            int hi = h0 + dh;
            float whf = dh ? fh : (1.f - fh);
            bool vh = (hi >= 0) && (hi < HH);
            int hic = min(max(hi, 0), HH - 1);
#pragma unroll
            for (int dw_ = 0; dw_ < 2; ++dw_) {
                int wi = w0 + dw_;
                float wwf = dw_ ? fw : (1.f - fw);
                bool vw = (wi >= 0) && (wi < WW);
                int wic = min(max(wi, 0), WW - 1);
                float coef = whf * wwf * ((vh && vw) ? 1.f : 0.f);
                const float* xp = x + (size_t)(b * CC) * THW + pt * HW
                                + hic * WW + wic;
#pragma unroll
                for (int c = 0; c < CC; ++c)
                    val[c] = fmaf(coef, xp[(size_t)c * THW], val[c]);
            }
        }
#pragma unroll
        for (int c = 0; c < CC; ++c)
#pragma unroll
            for (int co = 0; co < CO; ++co)
                acc[co] = fmaf(val[c], weight[(size_t)(co * CC + c) * KK + k],
                               acc[co]);
    }
#pragma unroll
    for (int co = 0; co < CO; ++co)
        out[(size_t)(b * CO + co) * THW + s] = acc[co];
}

// ---------------------------------------------------------------------------
extern "C" void kernel_launch(void* const* d_in, const int* in_sizes, int n_in,
                              void* d_out, int out_size, void* d_ws, size_t ws_size,
                              hipStream_t stream) {
    const float* x      = (const float*)d_in[0];
    const float* temp   = (const float*)d_in[1];
    const float* weight = (const float*)d_in[2];
    const float* bias   = (const float*)d_in[3];
    float* out = (float*)d_out;

    const size_t xT_bytes = (size_t)BB * THW * CC * sizeof(_Float16); // 2 MiB
    const size_t wP_bytes = (size_t)KK * 8 * CO * sizeof(unsigned);   // 13824 B

    if (ws_size >= xT_bytes + wP_bytes) {
        _Float16* xT = (_Float16*)d_ws;
        unsigned* wP = (unsigned*)((char*)d_ws + xT_bytes);
        hipLaunchKernelGGL(prep, dim3(257), dim3(256), 0, stream,
                           x, weight, xT, wP);
        hipLaunchKernelGGL(deform_lds4, dim3(BB * TT * (HH / 2)), dim3(512),
                           0, stream, xT, temp, wP, bias, out);
    } else {
        hipLaunchKernelGGL(deform_global, dim3((BB * THW) / 256), dim3(256),
                           0, stream, x, temp, weight, bias, out);
    }
}

// Round 12
// 91.583 us; speedup vs baseline: 1.1597x; 1.1597x over previous
//
#include <hip/hip_runtime.h>

// Problem constants (from reference setup_inputs)
#define BB 2
#define CC 16
#define TT 8
#define HH 64
#define WW 64
#define CO 16
#define KK 27          // 3*3*3 taps
#define THW (TT*HH*WW) // 32768
#define HW  (HH*WW)    // 4096

typedef _Float16 h8   __attribute__((ext_vector_type(8)));   // 16 B
typedef _Float16 h16  __attribute__((ext_vector_type(16)));  // 32 B
typedef float    f32x2 __attribute__((ext_vector_type(2)));

#define NROW 13        // tile rows [h0-5, h0+7]  (covers |off| <= 4)
#define ROWB 2048      // bytes per staged row: 64 cols * 16 ch * 2 B
#define TILEB (3 * NROW * ROWB)   // 79872 B

// ---------------------------------------------------------------------------
// Prep: blocks [0,256): x [B,C,T,H,W] -> xT [B,T,H,W,C] fp16 (32 B/pos)
//       blocks [256,283): weight [Co,C,3,3,3] -> wT [k][c][co] fp32
// ---------------------------------------------------------------------------
__global__ __launch_bounds__(256) void prep(const float* __restrict__ x,
                                            const float* __restrict__ w,
                                            _Float16* __restrict__ xT,
                                            float* __restrict__ wT) {
    int bid = blockIdx.x;
    if (bid < 256) {
        int pos = bid * 256 + threadIdx.x;          // B*T*H*W = 65536
        int b = pos / THW;
        int s = pos - b * THW;
        h16 hv;
#pragma unroll
        for (int c = 0; c < CC; ++c)
            hv[c] = (_Float16)x[(size_t)(b * CC + c) * THW + s];
        *(h16*)(xT + (size_t)pos * CC) = hv;
    } else {
        int id = (bid - 256) * 256 + threadIdx.x;   // 27*256 = 6912
        if (id < KK * CC * CO) {
            int k  = id / (CC * CO);
            int c  = (id / CO) % CC;
            int co = id % CO;
            wT[id] = w[(size_t)(co * CC + c) * KK + k];
        }
    }
}

// XOR swizzle (proven R7/R10): spread bank-group bits; bijective; SAME
// function on write and read side.
__device__ __forceinline__ int swz(int rr, int c, int base) {
    int sw = ((((c >> 2) ^ rr) & 3) << 4) | (((c >> 4) & 1) << 6);
    return base ^ sw;
}

// ---------------------------------------------------------------------------
// Main: 512 threads = 8 waves = 2 output rows x 4 tap-groups; 64 pos/wave.
// EXACTLY the R10 structure (total 91.2, passed) with ONE change:
// #pragma unroll 2 on the tap loop. R7 showed this body wants 220 VGPR when
// fully unrolled; under the (512,4) cap of 128 that meant ~90 spilled regs
// -> ~190 MB scratch traffic -> the observed ~25 us main. Unroll 2 bounds
// live gather registers to ~2 taps (~110 VGPR) -> no spills, same occupancy
// (2 blocks/CU, 16 waves/CU).
// ---------------------------------------------------------------------------
__global__ __launch_bounds__(512, 4) void deform_lds2(
    const _Float16* __restrict__ xT, const float* __restrict__ temp,
    const float* __restrict__ wT, const float* __restrict__ bias,
    float* __restrict__ out)
{
    __shared__ __align__(16) char lds[TILEB];       // 79872 B

    int tid = threadIdx.x;
    int lane = tid & 63;
    int wid  = __builtin_amdgcn_readfirstlane(tid >> 6);   // 0..7
    int row  = wid >> 2;                            // output row 0/1
    int g    = wid & 3;                             // tap group 0..3
    int blk = blockIdx.x;                           // 512 = B*T*(H/2)
    int b   = blk >> 8;
    int rem = blk & 255;
    int t   = rem >> 5;
    int h0  = (rem & 31) * 2;
    int rlo = max(0, h0 - 5);
    int rhi = min(HH - 1, h0 + 7);

    int h = h0 + row;
    int w = lane;
    const float* tb = temp + (size_t)b * (2 * KK) * THW
                    + (size_t)t * HW + h * WW + w;

    // ---- issue this wave's tap offsets FIRST (latency hides under staging)
    float offh[7], offw[7];
#pragma unroll
    for (int i = 0; i < 7; ++i) {
        int k = g + 4 * i;
        if (k < KK) {
            offh[i] = tb[(size_t)(2 * k)     * THW];
            offw[i] = tb[(size_t)(2 * k + 1) * THW];
        }
    }

    // ---- cooperative staging: 4992 coalesced 16B chunks over 512 threads
    {
        const int nchunk = 3 * NROW * 128;          // 4992
#pragma unroll
        for (int it = 0; it < 10; ++it) {
            int chunk = tid + it * 512;
            if (chunk >= nchunk) break;
            int kt  = chunk / (NROW * 128);
            int r2  = chunk - kt * (NROW * 128);
            int rr  = r2 >> 7;
            int j   = r2 & 127;                     // 16B chunk in row
            int pt  = t - 1 + kt;
            int r   = rlo + rr;
            if (pt >= 0 && pt < TT && r <= rhi) {
                const h8* src = (const h8*)(xT +
                    (size_t)((b * TT + pt) * HW + r * WW) * CC) + j;
                int dst = kt * (NROW * ROWB) + rr * ROWB + j * 16;
                *(h8*)(lds + swz(rr, j >> 1, dst)) = *src;
            }
        }
    }
    __syncthreads();

    f32x2 acc2[8];
#pragma unroll
    for (int j = 0; j < 8; ++j) acc2[j] = f32x2{0.f, 0.f};

#pragma unroll 2
    for (int i = 0; i < 7; ++i) {
        int k = g + 4 * i;
        if (k >= KK) continue;                      // wave-uniform
        int kt = k / 9, kh = (k / 3) % 3, kw = k % 3;
        int pt = t - 1 + kt;                        // offset_t == 0 exactly
        if (pt < 0 || pt >= TT) continue;           // block-uniform

        float ph = (float)(h - 1 + kh) + offh[i];
        float pw = (float)(w - 1 + kw) + offw[i];
        float r0f = floorf(ph), w0f = floorf(pw);
        float fh = ph - r0f, fw = pw - w0f;
        int r0 = (int)r0f, w0i = (int)w0f;
        int r1 = r0 + 1, w1i = w0i + 1;
        bool vh0 = (unsigned)r0  < (unsigned)HH;
        bool vh1 = (unsigned)r1  < (unsigned)HH;
        bool vw0 = (unsigned)w0i < (unsigned)WW;
        bool vw1 = (unsigned)w1i < (unsigned)WW;
        float fh1 = 1.f - fh, fw1 = 1.f - fw;
        float c00 = fh1 * fw1 * ((vh0 && vw0) ? 1.f : 0.f);
        float c01 = fh1 * fw  * ((vh0 && vw1) ? 1.f : 0.f);
        float c10 = fh  * fw1 * ((vh1 && vw0) ? 1.f : 0.f);
        float c11 = fh  * fw  * ((vh1 && vw1) ? 1.f : 0.f);
        int cc0 = min(max(w0i, 0), WW - 1);
        int cc1 = min(max(w1i, 0), WW - 1);
        int rr0 = min(max(r0, rlo), rhi) - rlo;
        int rr1 = min(max(r1, rlo), rhi) - rlo;
        int pb = kt * (NROW * ROWB);

        h8 q00a = *(const h8*)(lds + swz(rr0, cc0, pb + rr0 * ROWB + cc0 * 32));
        h8 q00b = *(const h8*)(lds + swz(rr0, cc0, pb + rr0 * ROWB + cc0 * 32 + 16));
        h8 q01a = *(const h8*)(lds + swz(rr0, cc1, pb + rr0 * ROWB + cc1 * 32));
        h8 q01b = *(const h8*)(lds + swz(rr0, cc1, pb + rr0 * ROWB + cc1 * 32 + 16));
        h8 q10a = *(const h8*)(lds + swz(rr1, cc0, pb + rr1 * ROWB + cc0 * 32));
        h8 q10b = *(const h8*)(lds + swz(rr1, cc0, pb + rr1 * ROWB + cc0 * 32 + 16));
        h8 q11a = *(const h8*)(lds + swz(rr1, cc1, pb + rr1 * ROWB + cc1 * 32));
        h8 q11b = *(const h8*)(lds + swz(rr1, cc1, pb + rr1 * ROWB + cc1 * 32 + 16));

        // rare |off|>4 fallback: valid sample row outside staged tile
        bool ob0 = vh0 && (r0 < rlo || r0 > rhi);
        bool ob1 = vh1 && (r1 < rlo || r1 > rhi);
        if (__builtin_expect(__any(ob0 || ob1), 0)) {
            const h8* xg = (const h8*)(xT + (size_t)((b * TT + pt) * HW) * CC);
            if (ob0) {
                q00a = xg[(r0 * WW + cc0) * 2];
                q00b = xg[(r0 * WW + cc0) * 2 + 1];
                q01a = xg[(r0 * WW + cc1) * 2];
                q01b = xg[(r0 * WW + cc1) * 2 + 1];
            }
            if (ob1) {
                q10a = xg[(r1 * WW + cc0) * 2];
                q10b = xg[(r1 * WW + cc0) * 2 + 1];
                q11a = xg[(r1 * WW + cc1) * 2];
                q11b = xg[(r1 * WW + cc1) * 2 + 1];
            }
        }

        // packed fp16 bilinear interp
        _Float16 h00 = (_Float16)c00, h01 = (_Float16)c01;
        _Float16 h10 = (_Float16)c10, h11 = (_Float16)c11;
        h8 va = q00a * h00 + q01a * h01 + q10a * h10 + q11a * h11;
        h8 vb = q00b * h00 + q01b * h01 + q10b * h10 + q11b * h11;

        // contraction: acc[co] += val[c] * W[k][c][co] (weights -> s_load)
        const f32x2* wk = (const f32x2*)(wT + k * (CC * CO));
#pragma unroll
        for (int c = 0; c < 8; ++c) {
            float vl = (float)va[c];
            float vh = (float)vb[c];
#pragma unroll
            for (int jj = 0; jj < 8; ++jj) {
                acc2[jj] += wk[c * 8 + jj] * vl;
                acc2[jj] += wk[(c + 8) * 8 + jj] * vh;
            }
        }
    }

    // ---- cross-group reduction: reuse staging LDS (32 KB of it) ----
    __syncthreads();                                // all tap reads done
    float* red = (float*)lds;                       // [row][g][co][pos]
#pragma unroll
    for (int jj = 0; jj < 8; ++jj) {
        red[((row * 4 + g) * CO + 2 * jj)     * 64 + w] = acc2[jj][0];
        red[((row * 4 + g) * CO + 2 * jj + 1) * 64 + w] = acc2[jj][1];
    }
    __syncthreads();

#pragma unroll
    for (int it = 0; it < 4; ++it) {
        int idx = tid + it * 512;                   // 2048 (row,co,pos) outs
        int row2 = idx >> 10;
        int co   = (idx >> 6) & 15;
        int p    = idx & 63;
        float sum = bias[co];
#pragma unroll
        for (int gg = 0; gg < 4; ++gg)
            sum += red[((row2 * 4 + gg) * CO + co) * 64 + p];
        out[(size_t)b * CO * THW + (size_t)co * THW
            + t * HW + (h0 + row2) * WW + p] = sum;
    }
}

// ---------------------------------------------------------------------------
// Safety fallback if workspace is too small: direct fp32 global-gather.
// ---------------------------------------------------------------------------
__global__ __launch_bounds__(256) void deform_global(
    const float* __restrict__ x, const float* __restrict__ temp,
    const float* __restrict__ weight, const float* __restrict__ bias,
    float* __restrict__ out)
{
    int pos = blockIdx.x * 256 + threadIdx.x;
    int b = pos / THW, s = pos - b * THW;
    int t = s / HW, hw = s - t * HW, h = hw >> 6, w = hw & 63;
    float acc[CO];
#pragma unroll
    for (int co = 0; co < CO; ++co) acc[co] = bias[co];
#pragma unroll 1
    for (int k = 0; k < KK; ++k) {
        int kt = k / 9, kh = (k / 3) % 3, kw = k % 3;
        int pt = t - 1 + kt;
        if (pt < 0 || pt >= TT) continue;
        const float* tb = temp + (size_t)b * (2 * KK) * THW + s;
        float ph = (float)(h - 1 + kh) + tb[(size_t)(2 * k) * THW];
        float pw = (float)(w - 1 + kw) + tb[(size_t)(2 * k + 1) * THW];
        float h0f = floorf(ph), w0f = floorf(pw);
        float fh = ph - h0f, fw = pw - w0f;
        int h0 = (int)h0f, w0 = (int)w0f;
        float val[CC];
#pragma unroll
        for (int c = 0; c < CC; ++c) val[c] = 0.f;
#pragma unroll
        for (int dh = 0; dh < 2; ++dh) {
            int hi = h0 + dh;
            float whf = dh ? fh : (1.f - fh);
            bool vh = (hi >= 0) && (hi < HH);
            int hic = min(max(hi, 0), HH - 1);
#pragma unroll
            for (int dw_ = 0; dw_ < 2; ++dw_) {
                int wi = w0 + dw_;
                float wwf = dw_ ? fw : (1.f - fw);
                bool vw = (wi >= 0) && (wi < WW);
                int wic = min(max(wi, 0), WW - 1);
                float coef = whf * wwf * ((vh && vw) ? 1.f : 0.f);
                const float* xp = x + (size_t)(b * CC) * THW + pt * HW
                                + hic * WW + wic;
#pragma unroll
                for (int c = 0; c < CC; ++c)
                    val[c] = fmaf(coef, xp[(size_t)c * THW], val[c]);
            }
        }
#pragma unroll
        for (int c = 0; c < CC; ++c)
#pragma unroll
            for (int co = 0; co < CO; ++co)
                acc[co] = fmaf(val[c], weight[(size_t)(co * CC + c) * KK + k],
                               acc[co]);
    }
#pragma unroll
    for (int co = 0; co < CO; ++co)
        out[(size_t)(b * CO + co) * THW + s] = acc[co];
}

// ---------------------------------------------------------------------------
extern "C" void kernel_launch(void* const* d_in, const int* in_sizes, int n_in,
                              void* d_out, int out_size, void* d_ws, size_t ws_size,
                              hipStream_t stream) {
    const float* x      = (const float*)d_in[0];
    const float* temp   = (const float*)d_in[1];
    const float* weight = (const float*)d_in[2];
    const float* bias   = (const float*)d_in[3];
    float* out = (float*)d_out;

    const size_t xT_bytes = (size_t)BB * THW * CC * sizeof(_Float16); // 2 MiB
    const size_t wT_bytes = (size_t)KK * CC * CO * sizeof(float);     // 27 KiB

    if (ws_size >= xT_bytes + wT_bytes) {
        _Float16* xT = (_Float16*)d_ws;
        float*    wT = (float*)((char*)d_ws + xT_bytes);
        hipLaunchKernelGGL(prep, dim3(256 + 27), dim3(256), 0, stream,
                           x, weight, xT, wT);
        hipLaunchKernelGGL(deform_lds2, dim3(BB * TT * (HH / 2)), dim3(512),
                           0, stream, xT, temp, wT, bias, out);
    } else {
        hipLaunchKernelGGL(deform_global, dim3((BB * THW) / 256), dim3(256),
                           0, stream, x, temp, weight, bias, out);
    }
}